// Round 10
// baseline (123.703 us; speedup 1.0000x reference)
//
#include <hip/hip_runtime.h>
#include <hip/hip_bf16.h>
#include <math.h>

// ---------------------------------------------------------------------------
// SAContrastiveAdversarialLoss on MI355X (gfx950)
// B=8192, D=128, S=64. Output: scalar fp32.
//
// loss = sum_i -log(1e-12 + num_i/denom_i) / (B*(2B-1))
//        + sum_i -log(1e-12 + 1 - picked_i)
//
// v11 structure:
//  - Harness floor: ~43us 256MiB workspace re-poison fill inside the timed
//    region. Our kernels sit on top.
//  - main: v7 free-run skeleton + E11 SYMMETRY: e11[i][k]=e11[k][i], so only
//    upper-triangle 256-col tiles of e11 are computed; each tile's row-sums
//    AND col-sums are harvested (col-sums via transient cs + quad shfl +
//    per-wave LDS RMW + cross-wave reduce). 784 blocks (512 e12 + 272 e11)
//    vs 1024 -> ~24% less MFMA+exp work. Partial-slot invariant: 64 slots
//    per row, each written exactly once (e12: slot=J; e11 pair {a,o}: slot
//    32+o for rows-a, 32+a for rows-o; diagonal row-sums only).
//  - prep / final_adv / reduce: unchanged from v10.
// ---------------------------------------------------------------------------

#define NROWS 8192
#define DFEAT 128

typedef __bf16 bf16_t;
typedef __bf16 bf16x8 __attribute__((ext_vector_type(8)));
typedef __bf16 bf16x2 __attribute__((ext_vector_type(2)));
typedef float  f32x4  __attribute__((ext_vector_type(4)));

__device__ __forceinline__ float fexp2(float x) {
#if __has_builtin(__builtin_amdgcn_exp2f)
  return __builtin_amdgcn_exp2f(x);
#else
  return exp2f(x);
#endif
}

// async global->LDS, 16B per lane. gsrc is per-lane (includes +lane*16);
// lds dst is wave-uniform base (HW adds lane*16).
__device__ __forceinline__ void stage16(const void* gsrc, void* ldst) {
  __builtin_amdgcn_global_load_lds(
      (const __attribute__((address_space(1))) unsigned int*)gsrc,
      (__attribute__((address_space(3))) unsigned int*)ldst, 16, 0, 0);
}

// ---------------------------------------------------------------------------
// prep: block = 16 rows = one fragment-tile group, 256 threads (4 waves).
// Wave w normalizes rows 4w..4w+3 into padded LDS (stride 136 bf16 = 272B).
// Then 3 x 256 coalesced bf16x8 stores emit the A / K2 / K1 fragment tiles:
//   out[tile*2048 + u*8 + j] = L[u&15][(u>>6)*32 + ((u>>4)&3)*8 + j]
// matching the main kernel's fragment layout.
__global__ __launch_bounds__(256)
void sa_prep_kernel(const float* __restrict__ z1,
                    const float* __restrict__ z2,
                    bf16_t* __restrict__ Abuf,
                    bf16_t* __restrict__ Kc,
                    float* __restrict__ numv,
                    float* __restrict__ d11v) {
  __shared__ __align__(16) bf16_t L[3][16][136];

  int wave = threadIdx.x >> 6;   // 0..3
  int lane = threadIdx.x & 63;
  int tile = blockIdx.x;         // 0..511

  const float SCL = 14.426950408889634f;  // 10 * log2(e), folds /tau + exp2

#pragma unroll
  for (int r = 0; r < 4; ++r) {
    int rl  = wave * 4 + r;      // 0..15 row within tile
    int row = tile * 16 + rl;

    float2 a = ((const float2*)(z1 + (size_t)row * DFEAT))[lane];
    float2 b = ((const float2*)(z2 + (size_t)row * DFEAT))[lane];

    float s1  = a.x * a.x + a.y * a.y;
    float s2  = b.x * b.x + b.y * b.y;
    float s12 = a.x * b.x + a.y * b.y;
#pragma unroll
    for (int m = 32; m; m >>= 1) {
      s1  += __shfl_xor(s1, m, 64);
      s2  += __shfl_xor(s2, m, 64);
      s12 += __shfl_xor(s12, m, 64);
    }
    float r1 = 1.0f / fmaxf(sqrtf(s1), 1e-8f);  // COS_EPS
    float r2 = 1.0f / fmaxf(sqrtf(s2), 1e-8f);

    bf16x2 av;  av[0] = (bf16_t)(a.x * r1 * SCL); av[1] = (bf16_t)(a.y * r1 * SCL);
    bf16x2 k2v; k2v[0] = (bf16_t)(b.x * r2);      k2v[1] = (bf16_t)(b.y * r2);
    bf16x2 k1v; k1v[0] = (bf16_t)(a.x * r1);      k1v[1] = (bf16_t)(a.y * r1);

    *(bf16x2*)&L[0][rl][2 * lane] = av;
    *(bf16x2*)&L[1][rl][2 * lane] = k2v;
    *(bf16x2*)&L[2][rl][2 * lane] = k1v;

    if (lane == 0) {
      numv[row] = expf(10.0f * s12 * r1 * r2);
      d11v[row] = expf(10.0f * s1 * r1 * r1);
    }
  }
  __syncthreads();

  // Phase 2: 3 x 256 coalesced 16B stores (A, K2, K1 tiles).
#pragma unroll
  for (int sel = 0; sel < 3; ++sel) {
    int u   = threadIdx.x;       // 0..255
    int kf  = u >> 6;
    int qk  = (u >> 4) & 3;
    int r16 = u & 15;
    bf16x8 v = *(const bf16x8*)&L[sel][r16][kf * 32 + qk * 8];
    bf16_t* dst = (sel == 0) ? (Abuf + (size_t)tile * 2048)
                : (sel == 1) ? (Kc + (size_t)tile * 2048)
                             : (Kc + (size_t)(512 + tile) * 2048);
    *(bf16x8*)(dst + u * 8) = v;
  }
}

// ---------------------------------------------------------------------------
// main: fused "row-sum of exp(sim)" with e11 symmetry.
// 784 blocks: swz<512 -> e12 block (I=swz>>5, J=swz&31): rows 512I x n2-cols
// 256J, row-sums -> slot J. swz>=512 -> e11 upper-tri block (I,J from
// triangular decode, J<=2I+1): rows 512I x n1-cols 256J; strip a=2I+(w>>2):
//   a>J: row-sums -> slot 32+J, col-sums -> rows tile J at slot 32+a
//   a==J: row-sums only (diagonal); a<J: dead strip (no stores).
// Free-run v7 loop; col-sums via transient cs + 2 shfl + per-wave LDS RMW,
// then one extra barrier + cross-wave reduce + coalesced store.
// MFMA C/D layout: col=lane&15, row=(lane>>4)*4+reg.
__global__ __launch_bounds__(512, 4)
void sa_main_kernel(const bf16_t* __restrict__ Abuf,
                    const bf16_t* __restrict__ Kc,
                    float* __restrict__ T2t) {
  __shared__ __align__(16) bf16_t bsm[32768];   // 64KB staged chunk
  __shared__ float colred[8][256];              // 8KB per-wave col partials

  int wave = threadIdx.x >> 6;   // 0..7
  int lane = threadIdx.x & 63;
  int quad = lane >> 4;

  // bijective XCD swizzle over 784 = 8*98 blocks.
  int id  = blockIdx.x;
  int swz = (id & 7) * 98 + (id >> 3);

  int I, J, chunk;
  bool e11;
  if (swz < 512) {
    I = swz >> 5; J = swz & 31; chunk = J; e11 = false;
  } else {
    int m = swz - 512;           // 0..271, triangular: C(I)=I*(I+1)
    I = 0;
    while ((I + 1) * (I + 2) <= m) ++I;
    J = m - I * (I + 1);         // 0..2I+1
    chunk = 32 + J; e11 = true;
  }

  int rowBase = I * 512 + wave * 64;
  int aTile   = rowBase >> 8;            // 256-row tile = 2I + (wave>>2)
  bool alive  = !e11 || (aTile >= J);    // dead strip: a<J (J=2I+1, waves 0-3)

  // A fragments for this wave's 4 row-strips.
  const bf16x8* ap = (const bf16x8*)Abuf + (size_t)(rowBase >> 4) * 256 + lane;
  bf16x8 afrag[4][4];
#pragma unroll
  for (int s = 0; s < 4; ++s)
#pragma unroll
    for (int kfi = 0; kfi < 4; ++kfi)
      afrag[s][kfi] = ap[(s * 4 + kfi) * 64];

  // Stage the 64KB key chunk (n2 for e12, n1 for e11).
  const char* src = (const char*)Kc + (size_t)chunk * 65536 +
                    (size_t)wave * 8192 + (size_t)lane * 16;
  char* dst = (char*)&bsm[0] + wave * 8192;
#pragma unroll
  for (int i = 0; i < 8; ++i) stage16(src + i * 1024, dst + i * 1024);

  // zero this wave's col-partial row (own region; RMW only by own wave)
  *(f32x4*)&colred[wave][lane * 4] = (f32x4){0.f, 0.f, 0.f, 0.f};

  __syncthreads();  // staging + colred-zero rendezvous

  f32x4 sums[4];
#pragma unroll
  for (int s = 0; s < 4; ++s) sums[s] = (f32x4){0.f, 0.f, 0.f, 0.f};

  // 8 phases x 32 cols, rotated start per wave; no sync, waves free-run.
#pragma unroll 1
  for (int i = 0; i < 8; ++i) {
    int p = (wave + i) & 7;
    const bf16_t* base = &bsm[0] + p * 4096;
#pragma unroll
    for (int tt = 0; tt < 2; ++tt) {
      const bf16x8* bs = (const bf16x8*)(base + tt * 2048);
      bf16x8 bfr[4];
#pragma unroll
      for (int kfi = 0; kfi < 4; ++kfi) bfr[kfi] = bs[kfi * 64 + lane];
      float cs = 0.0f;
#pragma unroll
      for (int s = 0; s < 4; ++s) {
        f32x4 c = {0.f, 0.f, 0.f, 0.f};
        __builtin_amdgcn_s_setprio(1);
#pragma unroll
        for (int kfi = 0; kfi < 4; ++kfi)
          c = __builtin_amdgcn_mfma_f32_16x16x32_bf16(afrag[s][kfi], bfr[kfi],
                                                      c, 0, 0, 0);
        __builtin_amdgcn_s_setprio(0);
        float e0 = fexp2(c[0]), e1 = fexp2(c[1]);
        float e2 = fexp2(c[2]), e3 = fexp2(c[3]);
        sums[s][0] += e0; sums[s][1] += e1;
        sums[s][2] += e2; sums[s][3] += e3;
        cs += (e0 + e1) + (e2 + e3);
      }
      if (e11) {
        // col-sum for the 16 cols of this half-tile over the wave's 64 rows
        cs += __shfl_xor(cs, 16, 64);
        cs += __shfl_xor(cs, 32, 64);
        if (lane < 16)
          colred[wave][p * 32 + tt * 16 + lane] += cs;  // own-wave RMW
      }
    }
  }

  // Row-sums: reduce across 16 lanes of each quad-group, float4 store.
  int l15 = lane & 15;
  if (alive) {
#pragma unroll
    for (int s = 0; s < 4; ++s) {
      f32x4 st;
#pragma unroll
      for (int r = 0; r < 4; ++r) {
        float v = sums[s][r];
        v += __shfl_xor(v, 1, 64);
        v += __shfl_xor(v, 2, 64);
        v += __shfl_xor(v, 4, 64);
        v += __shfl_xor(v, 8, 64);
        st[r] = v;
      }
      if (l15 == 0)
        *(f32x4*)(T2t + (size_t)chunk * 8192 + rowBase + s * 16 + quad * 4) =
            st;
    }
  }

  // Col-sums: cross-wave reduce (waves 0-3 = strip 2I, 4-7 = strip 2I+1),
  // store to rows of tile J at slot 32+a (pair {a,J}, a>J only).
  __syncthreads();
  if (e11) {
    int t  = threadIdx.x;
    int g  = t >> 8;            // 0 or 1: which 256-row strip
    int cc = t & 255;           // col within chunk
    int a  = 2 * I + g;
    if (a > J) {
      float v = colred[g * 4 + 0][cc] + colred[g * 4 + 1][cc] +
                colred[g * 4 + 2][cc] + colred[g * 4 + 3][cc];
      T2t[(size_t)(32 + a) * 8192 + J * 256 + cc] = v;
    }
  }
}

// ---------------------------------------------------------------------------
// final+adv fused: 512 blocks x 256 threads; wave handles 4 rows (loop).
// Lane l contributes T2t[l][row] (L2-resident 2MB); summed in the same
// 64-lane butterfly as the adversarial argmax. Partial -> plain store.
__global__ __launch_bounds__(256)
void sa_final_adv_kernel(const float* __restrict__ T2t,
                         const float* __restrict__ numv,
                         const float* __restrict__ d11v,
                         const float* __restrict__ c,
                         const float* __restrict__ lab,
                         float* __restrict__ partial) {
  int wave = threadIdx.x >> 6;
  int lane = threadIdx.x & 63;

  float acc = 0.0f;
#pragma unroll
  for (int i = 0; i < 4; ++i) {
    int row = blockIdx.x * 16 + wave * 4 + i;

    float cv = c[row * 64 + lane];
    float lv = lab[row * 64 + lane];
    float tv = T2t[(size_t)lane * 8192 + row];  // 64 chunk-partials per row

    float ss = cv * cv;
    float bestv = lv;
    int   besti = lane;
#pragma unroll
    for (int m = 32; m; m >>= 1) {
      ss += __shfl_xor(ss, m, 64);
      tv += __shfl_xor(tv, m, 64);
      float ov = __shfl_xor(bestv, m, 64);
      int   oi = __shfl_xor(besti, m, 64);
      if (ov > bestv || (ov == bestv && oi < besti)) { bestv = ov; besti = oi; }
    }
    float picked = __shfl(cv, besti, 64) / fmaxf(sqrtf(ss), 1e-12f);

    if (lane == 0) {
      float denom = tv - d11v[row];  // tv = full row sum of both exp blocks
      acc += -logf(1e-12f + numv[row] / denom) * (1.0f / 134209536.0f)
             - logf(1e-12f + 1.0f - picked);  // LAM = 1
    }
  }

  __shared__ float wacc[4];
  if (lane == 0) wacc[wave] = acc;
  __syncthreads();
  if (threadIdx.x == 0)
    partial[blockIdx.x] = wacc[0] + wacc[1] + wacc[2] + wacc[3];
}

// ---------------------------------------------------------------------------
// reduce: single block sums the 512 block partials -> out (plain store).
__global__ __launch_bounds__(256)
void sa_reduce_kernel(const float* __restrict__ partial,
                      float* __restrict__ out) {
  float v = partial[threadIdx.x] + partial[threadIdx.x + 256];
#pragma unroll
  for (int m = 32; m; m >>= 1) v += __shfl_xor(v, m, 64);
  __shared__ float wacc[4];
  if ((threadIdx.x & 63) == 0) wacc[threadIdx.x >> 6] = v;
  __syncthreads();
  if (threadIdx.x == 0) out[0] = wacc[0] + wacc[1] + wacc[2] + wacc[3];
}

// ---------------------------------------------------------------------------
extern "C" void kernel_launch(void* const* d_in, const int* in_sizes, int n_in,
                              void* d_out, int out_size, void* d_ws,
                              size_t ws_size, hipStream_t stream) {
  const float* z1  = (const float*)d_in[0];  // [8192,128]
  const float* z2  = (const float*)d_in[1];  // [8192,128]
  const float* co  = (const float*)d_in[2];  // [8192,64]
  const float* lab = (const float*)d_in[3];  // [8192,64]
  float* out = (float*)d_out;

  char* ws = (char*)d_ws;
  bf16_t* Abuf  = (bf16_t*)ws;                           // 8192*128*2 = 2 MB
  bf16_t* Kc    = (bf16_t*)(ws + 2u * 1024 * 1024);      // 16384*128*2 = 4 MB
  float*  T2t   = (float*)(ws + 6u * 1024 * 1024);       // 64*8192*4 = 2 MB
  float*  numv  = (float*)(ws + 8u * 1024 * 1024);       // 32 KB
  float*  d11v  = numv + NROWS;                          // 32 KB
  float*  part  = d11v + NROWS;                          // 2 KB

  sa_prep_kernel<<<NROWS / 16, 256, 0, stream>>>(z1, z2, Abuf, Kc, numv,
                                                 d11v);
  sa_main_kernel<<<784, 512, 0, stream>>>(Abuf, Kc, T2t);
  sa_final_adv_kernel<<<NROWS / 16, 256, 0, stream>>>(T2t, numv, d11v, co,
                                                      lab, part);
  sa_reduce_kernel<<<1, 256, 0, stream>>>(part, out);
}

// Round 12
// 109.319 us; speedup vs baseline: 1.1316x; 1.1316x over previous
//
#include <hip/hip_runtime.h>
#include <hip/hip_bf16.h>
#include <math.h>

// ---------------------------------------------------------------------------
// SAContrastiveAdversarialLoss on MI355X (gfx950)
// B=8192, D=128, S=64. Output: scalar fp32.
//
// loss = sum_i -log(1e-12 + num_i/denom_i) / (B*(2B-1))
//        + sum_i -log(1e-12 + 1 - picked_i)
//
// v12 (resubmit; r11 was an infra failure, not a kernel verdict):
//  - Harness floor: ~43us 256MiB workspace re-poison fill inside the timed
//    region. Our kernels sit on top.
//  - main: v7 free-run skeleton with 16 waves x 32 rows/wave (was 8 x 64):
//    per-wave regs ~80 (afrag 32) -> 4 waves/SIMD resident (v7 ran at 2,
//    reg-band-capped at ~130). Same total staging as v7 (1024 blocks x 64KB;
//    v9's 32-rows attempt doubled staging and lost). Inner loop is v7's
//    verbatim minus 2 strips. 1024 blocks = 4 clean rounds at 1 block/CU.
//    v11 lesson: keep the inner loop pure {ds_read, MFMA, exp, private acc};
//    e11-symmetry bookkeeping in the loop cost more than 24% FLOP savings.
//  - prep: 512 blocks x 256 thr, LDS-staged coalesced fragment-tile stores.
//  - final_adv: 512 blocks x 256 thr, 4 rows/wave; partial plain stores;
//    1-block reduce -> out.
// ---------------------------------------------------------------------------

#define NROWS 8192
#define DFEAT 128

typedef __bf16 bf16_t;
typedef __bf16 bf16x8 __attribute__((ext_vector_type(8)));
typedef __bf16 bf16x2 __attribute__((ext_vector_type(2)));
typedef float  f32x4  __attribute__((ext_vector_type(4)));

__device__ __forceinline__ float fexp2(float x) {
#if __has_builtin(__builtin_amdgcn_exp2f)
  return __builtin_amdgcn_exp2f(x);
#else
  return exp2f(x);
#endif
}

// async global->LDS, 16B per lane. gsrc is per-lane (includes +lane*16);
// lds dst is wave-uniform base (HW adds lane*16).
__device__ __forceinline__ void stage16(const void* gsrc, void* ldst) {
  __builtin_amdgcn_global_load_lds(
      (const __attribute__((address_space(1))) unsigned int*)gsrc,
      (__attribute__((address_space(3))) unsigned int*)ldst, 16, 0, 0);
}

// ---------------------------------------------------------------------------
// prep: block = 16 rows = one fragment-tile group, 256 threads (4 waves).
// Wave w normalizes rows 4w..4w+3 into padded LDS (stride 136 bf16 = 272B).
// Then 3 x 256 coalesced bf16x8 stores emit the A / K2 / K1 fragment tiles:
//   out[tile*2048 + u*8 + j] = L[u&15][(u>>6)*32 + ((u>>4)&3)*8 + j]
// matching the main kernel's fragment layout.
__global__ __launch_bounds__(256)
void sa_prep_kernel(const float* __restrict__ z1,
                    const float* __restrict__ z2,
                    bf16_t* __restrict__ Abuf,
                    bf16_t* __restrict__ Kc,
                    float* __restrict__ numv,
                    float* __restrict__ d11v) {
  __shared__ __align__(16) bf16_t L[3][16][136];

  int wave = threadIdx.x >> 6;   // 0..3
  int lane = threadIdx.x & 63;
  int tile = blockIdx.x;         // 0..511

  const float SCL = 14.426950408889634f;  // 10 * log2(e), folds /tau + exp2

#pragma unroll
  for (int r = 0; r < 4; ++r) {
    int rl  = wave * 4 + r;      // 0..15 row within tile
    int row = tile * 16 + rl;

    float2 a = ((const float2*)(z1 + (size_t)row * DFEAT))[lane];
    float2 b = ((const float2*)(z2 + (size_t)row * DFEAT))[lane];

    float s1  = a.x * a.x + a.y * a.y;
    float s2  = b.x * b.x + b.y * b.y;
    float s12 = a.x * b.x + a.y * b.y;
#pragma unroll
    for (int m = 32; m; m >>= 1) {
      s1  += __shfl_xor(s1, m, 64);
      s2  += __shfl_xor(s2, m, 64);
      s12 += __shfl_xor(s12, m, 64);
    }
    float r1 = 1.0f / fmaxf(sqrtf(s1), 1e-8f);  // COS_EPS
    float r2 = 1.0f / fmaxf(sqrtf(s2), 1e-8f);

    bf16x2 av;  av[0] = (bf16_t)(a.x * r1 * SCL); av[1] = (bf16_t)(a.y * r1 * SCL);
    bf16x2 k2v; k2v[0] = (bf16_t)(b.x * r2);      k2v[1] = (bf16_t)(b.y * r2);
    bf16x2 k1v; k1v[0] = (bf16_t)(a.x * r1);      k1v[1] = (bf16_t)(a.y * r1);

    *(bf16x2*)&L[0][rl][2 * lane] = av;
    *(bf16x2*)&L[1][rl][2 * lane] = k2v;
    *(bf16x2*)&L[2][rl][2 * lane] = k1v;

    if (lane == 0) {
      numv[row] = expf(10.0f * s12 * r1 * r2);
      d11v[row] = expf(10.0f * s1 * r1 * r1);
    }
  }
  __syncthreads();

  // Phase 2: 3 x 256 coalesced 16B stores (A, K2, K1 tiles).
#pragma unroll
  for (int sel = 0; sel < 3; ++sel) {
    int u   = threadIdx.x;       // 0..255
    int kf  = u >> 6;
    int qk  = (u >> 4) & 3;
    int r16 = u & 15;
    bf16x8 v = *(const bf16x8*)&L[sel][r16][kf * 32 + qk * 8];
    bf16_t* dst = (sel == 0) ? (Abuf + (size_t)tile * 2048)
                : (sel == 1) ? (Kc + (size_t)tile * 2048)
                             : (Kc + (size_t)(512 + tile) * 2048);
    *(bf16x8*)(dst + u * 8) = v;
  }
}

// ---------------------------------------------------------------------------
// main: fused "row-sum of exp(sim)" over the virtual 8192x16384 matrix.
// Block = 512 rows x 256 cols; 16 waves; wave w owns rows [bx*512+w*32, +32).
// Prologue: whole 64KB chunk of Kc staged into LDS (4 x global_load_lds per
// wave), ONE __syncthreads, then barrier-free rotated free-run phases.
// Per-wave regs ~80 -> 4 waves/SIMD resident (2x v7).
// MFMA C/D layout: col=lane&15, row=(lane>>4)*4+reg.
// Partial row-sums -> T2t[by][row], float4-coalesced writer lanes.
__global__ __launch_bounds__(1024, 4)
void sa_main_kernel(const bf16_t* __restrict__ Abuf,
                    const bf16_t* __restrict__ Kc,
                    float* __restrict__ T2t) {
  __shared__ __align__(16) bf16_t bsm[32768];  // 64KB: 8 col-tiles x 8KB

  int wave = threadIdx.x >> 6;   // 0..15
  int lane = threadIdx.x & 63;
  int quad = lane >> 4;

  // bijective XCD swizzle: 1024 blocks, 8 XCDs, 128 each. Each XCD sweeps
  // 8 col-chunks (512KB of Kc) + all of A (2MB) -> L2-resident.
  int id     = blockIdx.x;
  int xcd    = id & 7;
  int within = id >> 3;                 // 0..127
  int by     = xcd * 8 + (within >> 4); // 0..63 col-chunk: 256 cols
  int bx     = within & 15;             // 0..15 row-block: 512 rows
  int rowBase = bx * 512 + wave * 32;

  // A fragments for this wave's 2 row-strips (fragment-tiled: consecutive
  // 1KB fragments, fully coalesced 16B/lane).
  const bf16x8* ap = (const bf16x8*)Abuf + (size_t)(rowBase >> 4) * 256 + lane;
  bf16x8 afrag[2][4];
#pragma unroll
  for (int s = 0; s < 2; ++s)
#pragma unroll
    for (int kfi = 0; kfi < 4; ++kfi)
      afrag[s][kfi] = ap[(s * 4 + kfi) * 64];

  // Stage the whole 64KB chunk: wave w covers bytes [w*4KB, (w+1)*4KB).
  const char* src = (const char*)Kc + (size_t)by * 65536 +
                    (size_t)wave * 4096 + (size_t)lane * 16;
  char* dst = (char*)&bsm[0] + wave * 4096;  // wave-uniform LDS dst
#pragma unroll
  for (int i = 0; i < 4; ++i) stage16(src + i * 1024, dst + i * 1024);

  __syncthreads();  // only barrier in the kernel; LDS read-only afterwards

  f32x4 sums[2];
#pragma unroll
  for (int s = 0; s < 2; ++s) sums[s] = (f32x4){0.f, 0.f, 0.f, 0.f};

  // 8 phases x 32 cols, rotated start per wave; no sync, waves free-run.
#pragma unroll 1
  for (int i = 0; i < 8; ++i) {
    int p = (wave + i) & 7;
    const bf16_t* base = &bsm[0] + p * 4096;
#pragma unroll
    for (int tt = 0; tt < 2; ++tt) {
      const bf16x8* bs = (const bf16x8*)(base + tt * 2048);
      bf16x8 bfr[4];
#pragma unroll
      for (int kfi = 0; kfi < 4; ++kfi) bfr[kfi] = bs[kfi * 64 + lane];
#pragma unroll
      for (int s = 0; s < 2; ++s) {
        f32x4 c = {0.f, 0.f, 0.f, 0.f};
        __builtin_amdgcn_s_setprio(1);
#pragma unroll
        for (int kfi = 0; kfi < 4; ++kfi)
          c = __builtin_amdgcn_mfma_f32_16x16x32_bf16(afrag[s][kfi], bfr[kfi],
                                                      c, 0, 0, 0);
        __builtin_amdgcn_s_setprio(0);
#pragma unroll
        for (int r = 0; r < 4; ++r) sums[s][r] += fexp2(c[r]);
      }
    }
  }

  // Reduce across the 16 lanes of each quad-group (cols); writer lane packs
  // its 4 row-sums into ONE float4 store (quads 0..3 -> contiguous 64B).
  int l15 = lane & 15;
#pragma unroll
  for (int s = 0; s < 2; ++s) {
    f32x4 st;
#pragma unroll
    for (int r = 0; r < 4; ++r) {
      float v = sums[s][r];
      v += __shfl_xor(v, 1, 64);
      v += __shfl_xor(v, 2, 64);
      v += __shfl_xor(v, 4, 64);
      v += __shfl_xor(v, 8, 64);
      st[r] = v;
    }
    if (l15 == 0)
      *(f32x4*)(T2t + (size_t)by * 8192 + rowBase + s * 16 + quad * 4) = st;
  }
}

// ---------------------------------------------------------------------------
// final+adv fused: 512 blocks x 256 threads; wave handles 4 rows (loop).
// Lane l contributes T2t[l][row] (L2-resident 2MB); summed in the same
// 64-lane butterfly as the adversarial argmax. Partial -> plain store.
__global__ __launch_bounds__(256)
void sa_final_adv_kernel(const float* __restrict__ T2t,
                         const float* __restrict__ numv,
                         const float* __restrict__ d11v,
                         const float* __restrict__ c,
                         const float* __restrict__ lab,
                         float* __restrict__ partial) {
  int wave = threadIdx.x >> 6;
  int lane = threadIdx.x & 63;

  float acc = 0.0f;
#pragma unroll
  for (int i = 0; i < 4; ++i) {
    int row = blockIdx.x * 16 + wave * 4 + i;

    float cv = c[row * 64 + lane];
    float lv = lab[row * 64 + lane];
    float tv = T2t[(size_t)lane * 8192 + row];  // 64 chunk-partials per row

    float ss = cv * cv;
    float bestv = lv;
    int   besti = lane;
#pragma unroll
    for (int m = 32; m; m >>= 1) {
      ss += __shfl_xor(ss, m, 64);
      tv += __shfl_xor(tv, m, 64);
      float ov = __shfl_xor(bestv, m, 64);
      int   oi = __shfl_xor(besti, m, 64);
      if (ov > bestv || (ov == bestv && oi < besti)) { bestv = ov; besti = oi; }
    }
    float picked = __shfl(cv, besti, 64) / fmaxf(sqrtf(ss), 1e-12f);

    if (lane == 0) {
      float denom = tv - d11v[row];  // tv = full row sum of both exp blocks
      acc += -logf(1e-12f + numv[row] / denom) * (1.0f / 134209536.0f)
             - logf(1e-12f + 1.0f - picked);  // LAM = 1
    }
  }

  __shared__ float wacc[4];
  if (lane == 0) wacc[wave] = acc;
  __syncthreads();
  if (threadIdx.x == 0)
    partial[blockIdx.x] = wacc[0] + wacc[1] + wacc[2] + wacc[3];
}

// ---------------------------------------------------------------------------
// reduce: single block sums the 512 block partials -> out (plain store).
__global__ __launch_bounds__(256)
void sa_reduce_kernel(const float* __restrict__ partial,
                      float* __restrict__ out) {
  float v = partial[threadIdx.x] + partial[threadIdx.x + 256];
#pragma unroll
  for (int m = 32; m; m >>= 1) v += __shfl_xor(v, m, 64);
  __shared__ float wacc[4];
  if ((threadIdx.x & 63) == 0) wacc[threadIdx.x >> 6] = v;
  __syncthreads();
  if (threadIdx.x == 0) out[0] = wacc[0] + wacc[1] + wacc[2] + wacc[3];
}

// ---------------------------------------------------------------------------
extern "C" void kernel_launch(void* const* d_in, const int* in_sizes, int n_in,
                              void* d_out, int out_size, void* d_ws,
                              size_t ws_size, hipStream_t stream) {
  const float* z1  = (const float*)d_in[0];  // [8192,128]
  const float* z2  = (const float*)d_in[1];  // [8192,128]
  const float* co  = (const float*)d_in[2];  // [8192,64]
  const float* lab = (const float*)d_in[3];  // [8192,64]
  float* out = (float*)d_out;

  char* ws = (char*)d_ws;
  bf16_t* Abuf  = (bf16_t*)ws;                           // 8192*128*2 = 2 MB
  bf16_t* Kc    = (bf16_t*)(ws + 2u * 1024 * 1024);      // 16384*128*2 = 4 MB
  float*  T2t   = (float*)(ws + 6u * 1024 * 1024);       // 64*8192*4 = 2 MB
  float*  numv  = (float*)(ws + 8u * 1024 * 1024);       // 32 KB
  float*  d11v  = numv + NROWS;                          // 32 KB
  float*  part  = d11v + NROWS;                          // 2 KB

  sa_prep_kernel<<<NROWS / 16, 256, 0, stream>>>(z1, z2, Abuf, Kc, numv,
                                                 d11v);
  sa_main_kernel<<<1024, 1024, 0, stream>>>(Abuf, Kc, T2t);
  sa_final_adv_kernel<<<NROWS / 16, 256, 0, stream>>>(T2t, numv, d11v, co,
                                                      lab, part);
  sa_reduce_kernel<<<1, 256, 0, stream>>>(part, out);
}